// Round 2
// baseline (37.438 us; speedup 1.0000x reference)
//
#include <hip/hip_runtime.h>

#define H_IMG   500
#define W_IMG   512
#define KPP     10
#define N_PTS   8192
#define TILE    16
#define TX_TILES 32              // 512/16
#define TY_TILES 32              // ceil(500/16); rows >= 500 masked at store
#define N_TILES (TX_TILES * TY_TILES)
#define CAP     256              // max pts per tile (center density ~40; overflow prob ~0)
#define IMG_ELEMS (H_IMG * W_IMG * 3)   // 768000

// ---------------------------------------------------------------------------
// Single fused kernel: one block per 16x16 tile.
// Phase 1: all 256 threads scan the 8192 points (strided), re-project, and
//          append tile-overlapping points to an LDS list (conservative bbox).
// Phase 2: one thread per pixel keeps a sorted top-KPP by (z, idx) in
//          registers (fully unrolled -> no scratch), then composites exactly
//          like the reference cumprod.
// Precision-critical ops replicate the reference f32 op order with FMA
// contraction off; the only sharp decision (d2 < r2) uses exact arithmetic,
// the cull is conservative.
// ---------------------------------------------------------------------------
__global__ __launch_bounds__(256) void pcd_fused_kernel(
        const float* __restrict__ pts,
        const float* __restrict__ feats,
        float* __restrict__ out) {
#pragma clang fp contract(off)
    __shared__ float4 sp[CAP];
    __shared__ int scnt;

    const int tile = blockIdx.x;
    const int w0 = (tile & (TX_TILES - 1)) * TILE;
    const int h0 = (tile >> 5) * TILE;

    if (threadIdx.x == 0) scnt = 0;
    __syncthreads();

    // tile pixel-sample bounds in NDC (xs/ys are DECREASING in w/h)
    const float xhi = -(2.0f * ((float)w0 + 0.5f) - 512.0f) / 500.0f;
    const float xlo = -(2.0f * ((float)(w0 + TILE - 1) + 0.5f) - 512.0f) / 500.0f;
    const float yhi = -(2.0f * ((float)h0 + 0.5f) - 500.0f) / 500.0f;
    const float ylo = -(2.0f * ((float)(h0 + TILE - 1) + 0.5f) - 500.0f) / 500.0f;

    const float R = 0.005f;
    const float M = 2.0e-4f;             // conservative slack >> fp rounding
    const float cxlo = xlo - R - M, cxhi = xhi + R + M;
    const float cylo = ylo - R - M, cyhi = yhi + R + M;

    // ---- Phase 1: cull into LDS ----
    for (int i = threadIdx.x; i < N_PTS; i += 256) {
        float x = pts[i * 3 + 0];
        float y = pts[i * 3 + 1];
        float z = pts[i * 3 + 2];
        // exact reference op order: u = -FX*x/z + PX ; xn = -(2u - W)/S_MIN
        float u  = -575.0f * x / z + 256.0f;
        float v  = -575.0f * y / z + 250.0f;
        float xn = -(2.0f * u - 512.0f) / 500.0f;
        float yn = -(2.0f * v - 500.0f) / 500.0f;
        bool keep = (z > 0.0f) & (xn > cxlo) & (xn < cxhi) & (yn > cylo) & (yn < cyhi);
        if (keep) {
            int p = atomicAdd(&scnt, 1);
            if (p < CAP) sp[p] = make_float4(xn, yn, z, __int_as_float(i));
        }
    }
    __syncthreads();

    int n = scnt;
    n = n < CAP ? n : CAP;

    // ---- Phase 2: per-pixel render ----
    const int tx = threadIdx.x & 15;
    const int ty = threadIdx.x >> 4;
    const int w = w0 + tx;
    const int h = h0 + ty;

    const float xs = -(2.0f * ((float)w + 0.5f) - 512.0f) / 500.0f;
    const float ys = -(2.0f * ((float)h + 0.5f) - 500.0f) / 500.0f;
    const float R2 = 0.005f * 0.005f;

    float zk[KPP];
    float dk[KPP];
    int   ik[KPP];
#pragma unroll
    for (int k = 0; k < KPP; ++k) { zk[k] = __builtin_inff(); dk[k] = 0.0f; ik[k] = 0x7fffffff; }

    for (int j = 0; j < n; ++j) {
        float4 p = sp[j];                 // uniform addr across wave -> LDS broadcast
        float dx = xs - p.x;
        float dy = ys - p.y;
        float dx2 = dx * dx;              // contract(off): separate roundings like numpy
        float dy2 = dy * dy;
        float d2 = dx2 + dy2;
        if (d2 < R2) {
            float cz = p.z, cd = d2;
            int ci = __float_as_int(p.w);
            // sorted bubble-insert: ascending (z, idx); static indices only
#pragma unroll
            for (int k = 0; k < KPP; ++k) {
                bool lt = (cz < zk[k]) || (cz == zk[k] && ci < ik[k]);
                float tz = zk[k], td = dk[k];
                int ti = ik[k];
                if (lt) {
                    zk[k] = cz; dk[k] = cd; ik[k] = ci;
                    cz = tz; cd = td; ci = ti;
                }
            }
        }
    }

    if (h < H_IMG) {
        float T = 1.0f;
        float c0 = 0.0f, c1 = 0.0f, c2 = 0.0f;
        const int base = h * W_IMG + w;
        float* zout = out + IMG_ELEMS + base * KPP;
#pragma unroll
        for (int k = 0; k < KPP; ++k) {
            bool ok = zk[k] < __builtin_inff();
            float wt = ok ? (1.0f - dk[k] / R2) : 0.0f;
            float a = wt * T;               // wts[k] * prev[k]
            if (ok) {
                int fi = ik[k] * 3;
                c0 += a * feats[fi + 0];
                c1 += a * feats[fi + 1];
                c2 += a * feats[fi + 2];
            }
            T = T * (1.0f - wt);
            zout[k] = ok ? zk[k] : -1.0f;
        }
        out[base * 3 + 0] = c0;
        out[base * 3 + 1] = c1;
        out[base * 3 + 2] = c2;
    }
}

// ---------------------------------------------------------------------------
extern "C" void kernel_launch(void* const* d_in, const int* in_sizes, int n_in,
                              void* d_out, int out_size, void* d_ws, size_t ws_size,
                              hipStream_t stream) {
    const float* points = (const float*)d_in[0];   // (8192, 3) f32
    const float* feats  = (const float*)d_in[1];   // (8192, 3) f32
    float* out = (float*)d_out;                    // 768000 img + 2560000 zbuf f32
    (void)d_ws; (void)ws_size;

    pcd_fused_kernel<<<N_TILES, 256, 0, stream>>>(points, feats, out);
}

// Round 3
// 34.042 us; speedup vs baseline: 1.0997x; 1.0997x over previous
//
#include <hip/hip_runtime.h>

#define H_IMG   500
#define W_IMG   512
#define KPP     10
#define N_PTS   8192
#define TILE    16
#define TX_TILES 32              // 512/16
#define TY_TILES 32              // ceil(500/16); rows >= 500 masked at store
#define N_TILES (TX_TILES * TY_TILES)
#define CAP     256              // max pts per tile (center density ~40; overflow prob ~0)
#define IMG_ELEMS (H_IMG * W_IMG * 3)   // 768000

// ---------------------------------------------------------------------------
// Single fused kernel, one block per 16x16 tile.
// Phase 1: 256 threads scan all 8192 points (strided), re-project with the
//          reference's exact f32 op order, append tile-overlapping points to
//          an LDS list (conservative bbox cull).
// Phase 2: one thread per pixel keeps a top-KPP by (z, idx) in THIRTY NAMED
//          SCALARS (round-2 used arrays -> compiler demoted them to scratch,
//          VGPR_Count=28 < 30 live values; 40us kernel). Branchless
//          cndmask bubble insert, fully straight-line.
// ---------------------------------------------------------------------------

// sorted bubble-insert stage: ascending (z, idx); branchless
#define INSERT(ZZ, DD, II)                                             \
    {                                                                  \
        bool lt = (cz < ZZ) || ((cz == ZZ) && (ci < II));              \
        float tz = ZZ, td = DD; int ti = II;                           \
        ZZ = lt ? cz : ZZ;  DD = lt ? cd : DD;  II = lt ? ci : II;     \
        cz = lt ? tz : cz;  cd = lt ? td : cd;  ci = lt ? ti : ci;     \
    }

// epilogue stage k: weight, composite, store zbuf
#define EMIT(K, ZZ, DD, II)                                            \
    {                                                                  \
        bool ok = ZZ < __builtin_inff();                               \
        float wt = ok ? (1.0f - DD / R2) : 0.0f;                       \
        float a = wt * T;                                              \
        if (ok) {                                                      \
            int fi = II * 3;                                           \
            c0 += a * feats[fi + 0];                                   \
            c1 += a * feats[fi + 1];                                   \
            c2 += a * feats[fi + 2];                                   \
        }                                                              \
        T = T * (1.0f - wt);                                           \
        zout[K] = ok ? ZZ : -1.0f;                                     \
    }

__global__ __launch_bounds__(256) void pcd_fused_kernel(
        const float* __restrict__ pts,
        const float* __restrict__ feats,
        float* __restrict__ out) {
#pragma clang fp contract(off)
    __shared__ float4 sp[CAP];
    __shared__ int scnt;

    const int tile = blockIdx.x;
    const int w0 = (tile & (TX_TILES - 1)) * TILE;
    const int h0 = (tile >> 5) * TILE;

    if (threadIdx.x == 0) scnt = 0;
    __syncthreads();

    // tile pixel-sample bounds in NDC (xs/ys DECREASE with w/h)
    const float xhi = -(2.0f * ((float)w0 + 0.5f) - 512.0f) / 500.0f;
    const float xlo = -(2.0f * ((float)(w0 + TILE - 1) + 0.5f) - 512.0f) / 500.0f;
    const float yhi = -(2.0f * ((float)h0 + 0.5f) - 500.0f) / 500.0f;
    const float ylo = -(2.0f * ((float)(h0 + TILE - 1) + 0.5f) - 500.0f) / 500.0f;

    const float R = 0.005f;
    const float M = 2.0e-4f;             // conservative slack >> fp rounding
    const float cxlo = xlo - R - M, cxhi = xhi + R + M;
    const float cylo = ylo - R - M, cyhi = yhi + R + M;

    // ---- Phase 1: cull into LDS ----
    for (int i = threadIdx.x; i < N_PTS; i += 256) {
        float x = pts[i * 3 + 0];
        float y = pts[i * 3 + 1];
        float z = pts[i * 3 + 2];
        // exact reference op order: u = -FX*x/z + PX ; xn = -(2u - W)/S_MIN
        float u  = -575.0f * x / z + 256.0f;
        float v  = -575.0f * y / z + 250.0f;
        float xn = -(2.0f * u - 512.0f) / 500.0f;
        float yn = -(2.0f * v - 500.0f) / 500.0f;
        bool keep = (z > 0.0f) & (xn > cxlo) & (xn < cxhi) & (yn > cylo) & (yn < cyhi);
        if (keep) {
            int p = atomicAdd(&scnt, 1);
            if (p < CAP) sp[p] = make_float4(xn, yn, z, __int_as_float(i));
        }
    }
    __syncthreads();

    int n = scnt;
    n = n < CAP ? n : CAP;

    // ---- Phase 2: per-pixel top-K in named registers ----
    const int tx = threadIdx.x & 15;
    const int ty = threadIdx.x >> 4;
    const int w = w0 + tx;
    const int h = h0 + ty;

    const float xs = -(2.0f * ((float)w + 0.5f) - 512.0f) / 500.0f;
    const float ys = -(2.0f * ((float)h + 0.5f) - 500.0f) / 500.0f;
    const float R2 = 0.005f * 0.005f;
    const float INF = __builtin_inff();

    float kz0 = INF, kz1 = INF, kz2 = INF, kz3 = INF, kz4 = INF;
    float kz5 = INF, kz6 = INF, kz7 = INF, kz8 = INF, kz9 = INF;
    float kd0 = 0, kd1 = 0, kd2 = 0, kd3 = 0, kd4 = 0;
    float kd5 = 0, kd6 = 0, kd7 = 0, kd8 = 0, kd9 = 0;
    int ki0 = 0x7fffffff, ki1 = 0x7fffffff, ki2 = 0x7fffffff, ki3 = 0x7fffffff, ki4 = 0x7fffffff;
    int ki5 = 0x7fffffff, ki6 = 0x7fffffff, ki7 = 0x7fffffff, ki8 = 0x7fffffff, ki9 = 0x7fffffff;

    for (int j = 0; j < n; ++j) {
        float4 p = sp[j];                 // uniform addr across wave -> LDS broadcast
        float dx = xs - p.x;
        float dy = ys - p.y;
        float dx2 = dx * dx;              // contract(off): separate roundings like numpy
        float dy2 = dy * dy;
        float d2 = dx2 + dy2;
        if (d2 < R2) {
            float cz = p.z, cd = d2;
            int ci = __float_as_int(p.w);
            INSERT(kz0, kd0, ki0);
            INSERT(kz1, kd1, ki1);
            INSERT(kz2, kd2, ki2);
            INSERT(kz3, kd3, ki3);
            INSERT(kz4, kd4, ki4);
            INSERT(kz5, kd5, ki5);
            INSERT(kz6, kd6, ki6);
            INSERT(kz7, kd7, ki7);
            INSERT(kz8, kd8, ki8);
            INSERT(kz9, kd9, ki9);
        }
    }

    if (h < H_IMG) {
        float T = 1.0f;
        float c0 = 0.0f, c1 = 0.0f, c2 = 0.0f;
        const int base = h * W_IMG + w;
        float* zout = out + IMG_ELEMS + base * KPP;
        EMIT(0, kz0, kd0, ki0);
        EMIT(1, kz1, kd1, ki1);
        EMIT(2, kz2, kd2, ki2);
        EMIT(3, kz3, kd3, ki3);
        EMIT(4, kz4, kd4, ki4);
        EMIT(5, kz5, kd5, ki5);
        EMIT(6, kz6, kd6, ki6);
        EMIT(7, kz7, kd7, ki7);
        EMIT(8, kz8, kd8, ki8);
        EMIT(9, kz9, kd9, ki9);
        out[base * 3 + 0] = c0;
        out[base * 3 + 1] = c1;
        out[base * 3 + 2] = c2;
    }
}

// ---------------------------------------------------------------------------
extern "C" void kernel_launch(void* const* d_in, const int* in_sizes, int n_in,
                              void* d_out, int out_size, void* d_ws, size_t ws_size,
                              hipStream_t stream) {
    const float* points = (const float*)d_in[0];   // (8192, 3) f32
    const float* feats  = (const float*)d_in[1];   // (8192, 3) f32
    float* out = (float*)d_out;                    // 768000 img + 2560000 zbuf f32
    (void)d_ws; (void)ws_size;

    pcd_fused_kernel<<<N_TILES, 256, 0, stream>>>(points, feats, out);
}

// Round 4
// 33.385 us; speedup vs baseline: 1.1214x; 1.0197x over previous
//
#include <hip/hip_runtime.h>

#define H_IMG   500
#define W_IMG   512
#define KPP     10
#define N_PTS   8192
#define TILE    16
#define TX_TILES 32              // 512/16
#define TY_TILES 32              // ceil(500/16); rows >= 500 masked at store
#define N_TILES (TX_TILES * TY_TILES)
#define CAP     256              // max pts per tile (center density ~30; overflow prob ~0)
#define IMG_ELEMS (H_IMG * W_IMG * 3)   // 768000

// ---------------------------------------------------------------------------
// Round-4 structure: the 34us floor was phase-1 redundant projection
// (1024 blocks x 8192 pts x 2 IEEE divides = ~60 VALU instrs/iter).
// Kernel A projects each point ONCE (bit-identical f32 op order) into d_ws.
// Kernel B per 16x16 tile: scan precomputed float4 (1 dwordx4 + 4 cmps/iter),
// LDS-append survivors, then per-pixel top-KPP in named registers.
// ---------------------------------------------------------------------------

// sorted bubble-insert stage: ascending (z, idx); branchless
#define INSERT(ZZ, DD, II)                                             \
    {                                                                  \
        bool lt = (cz < ZZ) || ((cz == ZZ) && (ci < II));              \
        float tz = ZZ, td = DD; int ti = II;                           \
        ZZ = lt ? cz : ZZ;  DD = lt ? cd : DD;  II = lt ? ci : II;     \
        cz = lt ? tz : cz;  cd = lt ? td : cd;  ci = lt ? ti : ci;     \
    }

// epilogue stage k: weight, composite, store zbuf
#define EMIT(K, ZZ, DD, II)                                            \
    {                                                                  \
        bool ok = ZZ < __builtin_inff();                               \
        float wt = ok ? (1.0f - DD / R2) : 0.0f;                       \
        float a = wt * T;                                              \
        if (ok) {                                                      \
            int fi = II * 3;                                           \
            c0 += a * feats[fi + 0];                                   \
            c1 += a * feats[fi + 1];                                   \
            c2 += a * feats[fi + 2];                                   \
        }                                                              \
        T = T * (1.0f - wt);                                           \
        zout[K] = ok ? ZZ : -1.0f;                                     \
    }

// ---- Kernel A: project all points once ----
__global__ __launch_bounds__(256) void pcd_proj_kernel(
        const float* __restrict__ pts, float4* __restrict__ proj) {
#pragma clang fp contract(off)
    int i = blockIdx.x * 256 + threadIdx.x;
    if (i >= N_PTS) return;
    float x = pts[i * 3 + 0];
    float y = pts[i * 3 + 1];
    float z = pts[i * 3 + 2];
    // exact reference op order: u = -FX*x/z + PX ; xn = -(2u - W)/S_MIN
    float u  = -575.0f * x / z + 256.0f;
    float v  = -575.0f * y / z + 250.0f;
    float xn = -(2.0f * u - 512.0f) / 500.0f;
    float yn = -(2.0f * v - 500.0f) / 500.0f;
    proj[i] = make_float4(xn, yn, z, __int_as_float(i));
}

// ---- Kernel B: per-tile cull + render ----
__global__ __launch_bounds__(256) void pcd_render_kernel(
        const float4* __restrict__ proj,
        const float* __restrict__ feats,
        float* __restrict__ out) {
#pragma clang fp contract(off)
    __shared__ float4 sp[CAP];
    __shared__ int scnt;

    const int tile = blockIdx.x;
    const int w0 = (tile & (TX_TILES - 1)) * TILE;
    const int h0 = (tile >> 5) * TILE;

    if (threadIdx.x == 0) scnt = 0;
    __syncthreads();

    // tile pixel-sample bounds in NDC (xs/ys DECREASE with w/h)
    const float xhi = -(2.0f * ((float)w0 + 0.5f) - 512.0f) / 500.0f;
    const float xlo = -(2.0f * ((float)(w0 + TILE - 1) + 0.5f) - 512.0f) / 500.0f;
    const float yhi = -(2.0f * ((float)h0 + 0.5f) - 500.0f) / 500.0f;
    const float ylo = -(2.0f * ((float)(h0 + TILE - 1) + 0.5f) - 500.0f) / 500.0f;

    const float R = 0.005f;
    const float M = 2.0e-4f;             // conservative slack >> fp rounding
    const float cxlo = xlo - R - M, cxhi = xhi + R + M;
    const float cylo = ylo - R - M, cyhi = yhi + R + M;

    // ---- Phase 1: cull precomputed projections into LDS ----
    for (int i = threadIdx.x; i < N_PTS; i += 256) {
        float4 q = proj[i];              // coalesced dwordx4
        bool keep = (q.z > 0.0f) & (q.x > cxlo) & (q.x < cxhi)
                  & (q.y > cylo) & (q.y < cyhi);
        if (keep) {
            int p = atomicAdd(&scnt, 1);
            if (p < CAP) sp[p] = q;
        }
    }
    __syncthreads();

    int n = scnt;
    n = n < CAP ? n : CAP;

    // ---- Phase 2: per-pixel top-K in named registers ----
    const int tx = threadIdx.x & 15;
    const int ty = threadIdx.x >> 4;
    const int w = w0 + tx;
    const int h = h0 + ty;

    const float xs = -(2.0f * ((float)w + 0.5f) - 512.0f) / 500.0f;
    const float ys = -(2.0f * ((float)h + 0.5f) - 500.0f) / 500.0f;
    const float R2 = 0.005f * 0.005f;
    const float INF = __builtin_inff();

    float kz0 = INF, kz1 = INF, kz2 = INF, kz3 = INF, kz4 = INF;
    float kz5 = INF, kz6 = INF, kz7 = INF, kz8 = INF, kz9 = INF;
    float kd0 = 0, kd1 = 0, kd2 = 0, kd3 = 0, kd4 = 0;
    float kd5 = 0, kd6 = 0, kd7 = 0, kd8 = 0, kd9 = 0;
    int ki0 = 0x7fffffff, ki1 = 0x7fffffff, ki2 = 0x7fffffff, ki3 = 0x7fffffff, ki4 = 0x7fffffff;
    int ki5 = 0x7fffffff, ki6 = 0x7fffffff, ki7 = 0x7fffffff, ki8 = 0x7fffffff, ki9 = 0x7fffffff;

    for (int j = 0; j < n; ++j) {
        float4 p = sp[j];                 // uniform addr across wave -> LDS broadcast
        float dx = xs - p.x;
        float dy = ys - p.y;
        float dx2 = dx * dx;              // contract(off): separate roundings like numpy
        float dy2 = dy * dy;
        float d2 = dx2 + dy2;
        if (d2 < R2) {
            float cz = p.z, cd = d2;
            int ci = __float_as_int(p.w);
            INSERT(kz0, kd0, ki0);
            INSERT(kz1, kd1, ki1);
            INSERT(kz2, kd2, ki2);
            INSERT(kz3, kd3, ki3);
            INSERT(kz4, kd4, ki4);
            INSERT(kz5, kd5, ki5);
            INSERT(kz6, kd6, ki6);
            INSERT(kz7, kd7, ki7);
            INSERT(kz8, kd8, ki8);
            INSERT(kz9, kd9, ki9);
        }
    }

    if (h < H_IMG) {
        float T = 1.0f;
        float c0 = 0.0f, c1 = 0.0f, c2 = 0.0f;
        const int base = h * W_IMG + w;
        float* zout = out + IMG_ELEMS + base * KPP;
        EMIT(0, kz0, kd0, ki0);
        EMIT(1, kz1, kd1, ki1);
        EMIT(2, kz2, kd2, ki2);
        EMIT(3, kz3, kd3, ki3);
        EMIT(4, kz4, kd4, ki4);
        EMIT(5, kz5, kd5, ki5);
        EMIT(6, kz6, kd6, ki6);
        EMIT(7, kz7, kd7, ki7);
        EMIT(8, kz8, kd8, ki8);
        EMIT(9, kz9, kd9, ki9);
        out[base * 3 + 0] = c0;
        out[base * 3 + 1] = c1;
        out[base * 3 + 2] = c2;
    }
}

// ---------------------------------------------------------------------------
extern "C" void kernel_launch(void* const* d_in, const int* in_sizes, int n_in,
                              void* d_out, int out_size, void* d_ws, size_t ws_size,
                              hipStream_t stream) {
    const float* points = (const float*)d_in[0];   // (8192, 3) f32
    const float* feats  = (const float*)d_in[1];   // (8192, 3) f32
    float* out = (float*)d_out;                    // 768000 img + 2560000 zbuf f32

    float4* proj = (float4*)d_ws;                  // 8192 * 16 B

    pcd_proj_kernel<<<N_PTS / 256, 256, 0, stream>>>(points, proj);
    pcd_render_kernel<<<N_TILES, 256, 0, stream>>>(proj, feats, out);
}